// Round 1
// baseline (148.648 us; speedup 1.0000x reference)
//
#include <hip/hip_runtime.h>
#include <math.h>

#define BLOCK 256
#define CHUNKS 16

// ---------------------------------------------------------------------------
// Pass A: pack refs as (x, y, z, r2) float4 so the scan loop can fetch one
// candidate with a single wave-uniform s_load_dwordx4.
// r2 computed with the same op order as np.sum(ref*ref, axis=-1): (x*x+y*y)+z*z
// ---------------------------------------------------------------------------
__global__ __launch_bounds__(BLOCK) void prep_refs(
    const float* __restrict__ ref, float4* __restrict__ refs4, int Nr) {
#pragma clang fp contract(off)
    int j = blockIdx.x * BLOCK + threadIdx.x;
    if (j < Nr) {
        float x = ref[j * 3 + 0];
        float y = ref[j * 3 + 1];
        float z = ref[j * 3 + 2];
        float r2 = (x * x + y * y) + z * z;
        refs4[j] = make_float4(x, y, z, r2);
    }
}

// ---------------------------------------------------------------------------
// Pass B: each thread owns one query, scans one ref chunk (block-uniform j so
// refs come through SGPRs), keeps running top-3 by clamped d2.
// Formula matches reference exactly:
//   dot = fma(qz,rz, fma(qy,ry, qx*rx))   (ascending-k FMA chain)
//   d2  = (q2 + r2) - (2*dot)             (no contraction)
//   d2c = max(d2, 0)
// Tie-break: strict '<' while scanning ascending j == lower index wins,
// matching jax.lax.top_k.
// ---------------------------------------------------------------------------
__global__ __launch_bounds__(BLOCK) void knn_scan(
    const float* __restrict__ qpts, const float4* __restrict__ refs4,
    float* __restrict__ cd, int* __restrict__ ci,
    int Nq, int Nr, int chunk) {
#pragma clang fp contract(off)
    int qi = blockIdx.x * BLOCK + threadIdx.x;
    int c  = blockIdx.y;
    int jbeg = c * chunk;
    int jend = jbeg + chunk;
    if (jend > Nr) jend = Nr;

    float qx = 0.f, qy = 0.f, qz = 0.f;
    if (qi < Nq) {
        qx = qpts[qi * 3 + 0];
        qy = qpts[qi * 3 + 1];
        qz = qpts[qi * 3 + 2];
    }
    float q2 = (qx * qx + qy * qy) + qz * qz;

    const float FINF = __builtin_inff();
    float e0 = FINF, e1 = FINF, e2 = FINF;
    int   i0 = 0x7fffffff, i1 = 0x7fffffff, i2 = 0x7fffffff;

#pragma unroll 4
    for (int j = jbeg; j < jend; ++j) {
        float4 r = refs4[j];           // wave-uniform -> s_load_dwordx4
        float t = qx * r.x;
        t = fmaf(qy, r.y, t);
        t = fmaf(qz, r.z, t);
        float u  = 2.0f * t;
        float a  = q2 + r.w;
        float d2 = a - u;
        float d  = fmaxf(d2, 0.0f);
        if (d < e2) {                  // rare: wave skips via s_cbranch_vccz
            if (d < e1) {
                e2 = e1; i2 = i1;
                if (d < e0) { e1 = e0; i1 = i0; e0 = d; i0 = j; }
                else        { e1 = d;  i1 = j; }
            } else { e2 = d; i2 = j; }
        }
    }

    if (qi < Nq) {
        size_t base = (size_t)(c * 3) * (size_t)Nq + (size_t)qi; // [c][slot][q]
        cd[base]                 = e0;
        cd[base + (size_t)Nq]    = e1;
        cd[base + 2*(size_t)Nq]  = e2;
        ci[base]                 = i0;
        ci[base + (size_t)Nq]    = i1;
        ci[base + 2*(size_t)Nq]  = i2;
    }
}

// ---------------------------------------------------------------------------
// Pass C: merge CHUNKS*3 candidates per query (lexicographic (d, idx) to
// reproduce top_k tie behavior), then dist/weights/normalize/gather, matching
// reference op order:
//   dist = sqrt(d2c); w = 1/(dist + 1e-8); w /= ((w0+w1)+w2);
//   out  = (w0*f0 + w1*f1) + w2*f2   per component
// ---------------------------------------------------------------------------
__global__ __launch_bounds__(BLOCK) void knn_finish(
    const float* __restrict__ flow, const float* __restrict__ cd,
    const int* __restrict__ ci, float* __restrict__ out,
    int Nq, int nCand) {
#pragma clang fp contract(off)
    int qi = blockIdx.x * BLOCK + threadIdx.x;
    if (qi >= Nq) return;

    const float FINF = __builtin_inff();
    float bd0 = FINF, bd1 = FINF, bd2 = FINF;
    int   bi0 = 0x7fffffff, bi1 = 0x7fffffff, bi2 = 0x7fffffff;

    for (int s = 0; s < nCand; ++s) {
        float d  = cd[(size_t)s * (size_t)Nq + (size_t)qi];
        int   ix = ci[(size_t)s * (size_t)Nq + (size_t)qi];
        bool lt2 = (d < bd2) || (d == bd2 && ix < bi2);
        if (lt2) {
            bool lt1 = (d < bd1) || (d == bd1 && ix < bi1);
            if (lt1) {
                bd2 = bd1; bi2 = bi1;
                bool lt0 = (d < bd0) || (d == bd0 && ix < bi0);
                if (lt0) { bd1 = bd0; bi1 = bi0; bd0 = d; bi0 = ix; }
                else     { bd1 = d;  bi1 = ix; }
            } else { bd2 = d; bi2 = ix; }
        }
    }

    float s0 = sqrtf(bd0);
    float s1 = sqrtf(bd1);
    float s2 = sqrtf(bd2);
    float w0 = 1.0f / (s0 + 1e-8f);
    float w1 = 1.0f / (s1 + 1e-8f);
    float w2 = 1.0f / (s2 + 1e-8f);
    float wsum = (w0 + w1) + w2;
    w0 = w0 / wsum;
    w1 = w1 / wsum;
    w2 = w2 / wsum;

    float f0x = flow[bi0 * 3 + 0], f0y = flow[bi0 * 3 + 1], f0z = flow[bi0 * 3 + 2];
    float f1x = flow[bi1 * 3 + 0], f1y = flow[bi1 * 3 + 1], f1z = flow[bi1 * 3 + 2];
    float f2x = flow[bi2 * 3 + 0], f2y = flow[bi2 * 3 + 1], f2z = flow[bi2 * 3 + 2];

    out[qi * 3 + 0] = (w0 * f0x + w1 * f1x) + w2 * f2x;
    out[qi * 3 + 1] = (w0 * f0y + w1 * f1y) + w2 * f2y;
    out[qi * 3 + 2] = (w0 * f0z + w1 * f1z) + w2 * f2z;
}

extern "C" void kernel_launch(void* const* d_in, const int* in_sizes, int n_in,
                              void* d_out, int out_size, void* d_ws, size_t ws_size,
                              hipStream_t stream) {
    const float* q    = (const float*)d_in[0];
    const float* ref  = (const float*)d_in[1];
    const float* flow = (const float*)d_in[2];
    // d_in[3] is k == 3 (hardcoded)
    float* out = (float*)d_out;

    int Nq = in_sizes[0] / 3;
    int Nr = in_sizes[1] / 3;

    char* ws = (char*)d_ws;
    float4* refs4 = (float4*)ws;
    size_t off = (size_t)Nr * sizeof(float4);
    float* cd = (float*)(ws + off);
    off += (size_t)CHUNKS * 3 * (size_t)Nq * sizeof(float);
    int* ci = (int*)(ws + off);

    int chunk = (Nr + CHUNKS - 1) / CHUNKS;

    prep_refs<<<(Nr + BLOCK - 1) / BLOCK, BLOCK, 0, stream>>>(ref, refs4, Nr);

    dim3 grid((Nq + BLOCK - 1) / BLOCK, CHUNKS);
    knn_scan<<<grid, BLOCK, 0, stream>>>(q, refs4, cd, ci, Nq, Nr, chunk);

    knn_finish<<<(Nq + BLOCK - 1) / BLOCK, BLOCK, 0, stream>>>(
        flow, cd, ci, out, Nq, CHUNKS * 3);
}

// Round 2
// 146.213 us; speedup vs baseline: 1.0167x; 1.0167x over previous
//
#include <hip/hip_runtime.h>
#include <math.h>

#define BLOCK 256

// ---------------------------------------------------------------------------
// Pass A: pack refs as (x, y, z, r2) float4 so the scan loop fetches one
// candidate with a single wave-uniform s_load_dwordx4 (refs live in SGPRs).
// r2 op order matches np.sum(ref*ref, axis=-1): (x*x + y*y) + z*z
// ---------------------------------------------------------------------------
__global__ __launch_bounds__(BLOCK) void prep_refs(
    const float* __restrict__ ref, float4* __restrict__ refs4, int Nr) {
#pragma clang fp contract(off)
    int j = blockIdx.x * BLOCK + threadIdx.x;
    if (j < Nr) {
        float x = ref[j * 3 + 0];
        float y = ref[j * 3 + 1];
        float z = ref[j * 3 + 2];
        float r2 = (x * x + y * y) + z * z;
        refs4[j] = make_float4(x, y, z, r2);
    }
}

// ---------------------------------------------------------------------------
// Pass B: one thread = one query; scans one ref chunk (block-uniform j ->
// s_load path). Running top-3 kept in registers.
//
// Numerics identical to reference:
//   dot = fmaf(qz,rz, fmaf(qy,ry, qx*rx))
//   d2  = fmaf(-2, dot, q2 + r2)   == (q2+r2) - 2*dot  (2*dot exact, 1 rnd)
//   d   = max(d2, 0)
// Insert path: wave-uniform skip via __any (s_cbranch_vccz), then a fully
// branchless cndmask insertion (no divergent control flow).
// Tie-break: strict '<' scanning ascending j == lower index wins (jax top_k).
// ---------------------------------------------------------------------------
__global__ __launch_bounds__(BLOCK) void knn_scan(
    const float* __restrict__ qpts, const float4* __restrict__ refs4,
    float* __restrict__ cd, int* __restrict__ ci,
    int Nq, int Nr, int chunk) {
#pragma clang fp contract(off)
    int qi = blockIdx.x * BLOCK + threadIdx.x;
    int c  = blockIdx.y;
    int jbeg = c * chunk;
    int jend = jbeg + chunk;
    if (jend > Nr) jend = Nr;

    float qx = 0.f, qy = 0.f, qz = 0.f;
    if (qi < Nq) {
        qx = qpts[qi * 3 + 0];
        qy = qpts[qi * 3 + 1];
        qz = qpts[qi * 3 + 2];
    }
    float q2 = (qx * qx + qy * qy) + qz * qz;

    const float FINF = __builtin_inff();
    float e0 = FINF, e1 = FINF, e2 = FINF;
    int   i0 = 0x7fffffff, i1 = 0x7fffffff, i2 = 0x7fffffff;

#pragma unroll 8
    for (int j = jbeg; j < jend; ++j) {
        float4 r = refs4[j];               // wave-uniform -> s_load_dwordx4
        float t = qx * r.x;
        t = fmaf(qy, r.y, t);
        t = fmaf(qz, r.z, t);
        float a  = q2 + r.w;
        float d2 = fmaf(-2.0f, t, a);      // == a - 2*t exactly
        float d  = fmaxf(d2, 0.0f);
        if (__any(d < e2)) {               // uniform branch: s_cbranch_vccz
            bool c0 = d < e0;
            bool c1 = d < e1;
            bool c2 = d < e2;
            float ne2 = c1 ? e1 : (c2 ? d : e2);
            int   ni2 = c1 ? i1 : (c2 ? j : i2);
            float ne1 = c0 ? e0 : (c1 ? d : e1);
            int   ni1 = c0 ? i0 : (c1 ? j : i1);
            float ne0 = c0 ? d  : e0;
            int   ni0 = c0 ? j  : i0;
            e0 = ne0; e1 = ne1; e2 = ne2;
            i0 = ni0; i1 = ni1; i2 = ni2;
        }
    }

    if (qi < Nq) {
        size_t base = (size_t)(c * 3) * (size_t)Nq + (size_t)qi; // [c][slot][q]
        cd[base]                 = e0;
        cd[base + (size_t)Nq]    = e1;
        cd[base + 2*(size_t)Nq]  = e2;
        ci[base]                 = i0;
        ci[base + (size_t)Nq]    = i1;
        ci[base + 2*(size_t)Nq]  = i2;
    }
}

// ---------------------------------------------------------------------------
// Pass C: merge nCand candidates per query (lexicographic (d, idx) to match
// top_k tie behavior), then dist/weights/normalize/gather in reference order:
//   dist = sqrt(d2c); w = 1/(dist + 1e-8); w /= ((w0+w1)+w2);
//   out  = (w0*f0 + w1*f1) + w2*f2   per component
// ---------------------------------------------------------------------------
__global__ __launch_bounds__(BLOCK) void knn_finish(
    const float* __restrict__ flow, const float* __restrict__ cd,
    const int* __restrict__ ci, float* __restrict__ out,
    int Nq, int nCand) {
#pragma clang fp contract(off)
    int qi = blockIdx.x * BLOCK + threadIdx.x;
    if (qi >= Nq) return;

    const float FINF = __builtin_inff();
    float bd0 = FINF, bd1 = FINF, bd2 = FINF;
    int   bi0 = 0x7fffffff, bi1 = 0x7fffffff, bi2 = 0x7fffffff;

    for (int s = 0; s < nCand; ++s) {
        float d  = cd[(size_t)s * (size_t)Nq + (size_t)qi];
        int   ix = ci[(size_t)s * (size_t)Nq + (size_t)qi];
        bool lt2 = (d < bd2) || (d == bd2 && ix < bi2);
        bool lt1 = (d < bd1) || (d == bd1 && ix < bi1);
        bool lt0 = (d < bd0) || (d == bd0 && ix < bi0);
        float nd2 = lt1 ? bd1 : (lt2 ? d : bd2);
        int   ni2 = lt1 ? bi1 : (lt2 ? ix : bi2);
        float nd1 = lt0 ? bd0 : (lt1 ? d : bd1);
        int   ni1 = lt0 ? bi0 : (lt1 ? ix : bi1);
        float nd0 = lt0 ? d  : bd0;
        int   ni0 = lt0 ? ix : bi0;
        bd0 = nd0; bd1 = nd1; bd2 = nd2;
        bi0 = ni0; bi1 = ni1; bi2 = ni2;
    }

    float s0 = sqrtf(bd0);
    float s1 = sqrtf(bd1);
    float s2 = sqrtf(bd2);
    float w0 = 1.0f / (s0 + 1e-8f);
    float w1 = 1.0f / (s1 + 1e-8f);
    float w2 = 1.0f / (s2 + 1e-8f);
    float wsum = (w0 + w1) + w2;
    w0 = w0 / wsum;
    w1 = w1 / wsum;
    w2 = w2 / wsum;

    float f0x = flow[bi0 * 3 + 0], f0y = flow[bi0 * 3 + 1], f0z = flow[bi0 * 3 + 2];
    float f1x = flow[bi1 * 3 + 0], f1y = flow[bi1 * 3 + 1], f1z = flow[bi1 * 3 + 2];
    float f2x = flow[bi2 * 3 + 0], f2y = flow[bi2 * 3 + 1], f2z = flow[bi2 * 3 + 2];

    out[qi * 3 + 0] = (w0 * f0x + w1 * f1x) + w2 * f2x;
    out[qi * 3 + 1] = (w0 * f0y + w1 * f1y) + w2 * f2y;
    out[qi * 3 + 2] = (w0 * f0z + w1 * f1z) + w2 * f2z;
}

extern "C" void kernel_launch(void* const* d_in, const int* in_sizes, int n_in,
                              void* d_out, int out_size, void* d_ws, size_t ws_size,
                              hipStream_t stream) {
    const float* q    = (const float*)d_in[0];
    const float* ref  = (const float*)d_in[1];
    const float* flow = (const float*)d_in[2];
    float* out = (float*)d_out;

    int Nq = in_sizes[0] / 3;
    int Nr = in_sizes[1] / 3;

    // Pick CHUNKS to fit workspace: refs4 + CHUNKS*3*Nq*(float+int)
    int chunks = 32;
    while (chunks > 4) {
        size_t need = (size_t)Nr * sizeof(float4)
                    + (size_t)chunks * 3 * (size_t)Nq * (sizeof(float) + sizeof(int));
        if (need <= ws_size) break;
        chunks >>= 1;
    }

    char* ws = (char*)d_ws;
    float4* refs4 = (float4*)ws;
    size_t off = (size_t)Nr * sizeof(float4);
    float* cd = (float*)(ws + off);
    off += (size_t)chunks * 3 * (size_t)Nq * sizeof(float);
    int* ci = (int*)(ws + off);

    int chunk = (Nr + chunks - 1) / chunks;

    prep_refs<<<(Nr + BLOCK - 1) / BLOCK, BLOCK, 0, stream>>>(ref, refs4, Nr);

    dim3 grid((Nq + BLOCK - 1) / BLOCK, chunks);
    knn_scan<<<grid, BLOCK, 0, stream>>>(q, refs4, cd, ci, Nq, Nr, chunk);

    knn_finish<<<(Nq + BLOCK - 1) / BLOCK, BLOCK, 0, stream>>>(
        flow, cd, ci, out, Nq, chunks * 3);
}